// Round 6
// baseline (2787.465 us; speedup 1.0000x reference)
//
#include <hip/hip_runtime.h>
#include <hip/hip_bf16.h>

typedef __hip_bfloat16 bf16;
typedef __bf16 bf16x8_t __attribute__((ext_vector_type(8)));
typedef float f32x4_t __attribute__((ext_vector_type(4)));
typedef unsigned short u16x8_t __attribute__((ext_vector_type(8)));

#define HID 3584
#define SEQ 2048
#define NBATCH 2
#define MTOK 4096
#define NHEADS 16
#define NKVH 8
#define HDIM 256
#define QOUT 4096
#define KOUT 2048
#define INTERD 14336
#define EPSF 1e-6f

static __device__ __forceinline__ unsigned short f2bu(float f) {
  union { bf16 b; unsigned short u; } cv;
  cv.b = __float2bfloat16(f);
  return cv.u;
}

static __device__ __forceinline__ f32x4_t mfma16(bf16x8_t a, bf16x8_t b, f32x4_t c) {
  return __builtin_amdgcn_mfma_f32_16x16x32_bf16(a, b, c, 0, 0, 0);
}

static __device__ __forceinline__ void gl_lds16(const void* g, void* l) {
  __builtin_amdgcn_global_load_lds((__attribute__((address_space(1))) void*)g,
                                   (__attribute__((address_space(3))) void*)l,
                                   16, 0, 0);
}

static __device__ __forceinline__ float block_reduce_sum(float v) {
  __shared__ float buf[4];
  #pragma unroll
  for (int m = 1; m < 64; m <<= 1) v += __shfl_xor(v, m, 64);
  __syncthreads();
  if ((threadIdx.x & 63) == 0) buf[threadIdx.x >> 6] = v;
  __syncthreads();
  return buf[0] + buf[1] + buf[2] + buf[3];
}

// ---------------------------------------------------------------------------
// weight convert: f32 -> bf16
// ---------------------------------------------------------------------------
__global__ __launch_bounds__(256) void cvt_w(
    const float* __restrict__ src, bf16* __restrict__ dst, int n) {
  const int stride = gridDim.x * 256 * 8;
  for (int i = (blockIdx.x * 256 + threadIdx.x) * 8; i < n; i += stride) {
    const float4 a = *(const float4*)(src + i);
    const float4 b = *(const float4*)(src + i + 4);
    u16x8_t o;
    o[0] = f2bu(a.x); o[1] = f2bu(a.y); o[2] = f2bu(a.z); o[3] = f2bu(a.w);
    o[4] = f2bu(b.x); o[5] = f2bu(b.y); o[6] = f2bu(b.z); o[7] = f2bu(b.w);
    *(u16x8_t*)(dst + i) = o;
  }
}

// ---------------------------------------------------------------------------
// 8-phase 256x256 GEMM: C[M=4096][N] = A[M][K](bf16) * B[N][K](bf16)^T
// R5 schedule; R6 RACE FIX: the trailing wait of TILE(T) must leave only
// T+2's loads outstanding. When T+2 >= NT those stages were SKIPPED, so
// vmcnt(8) is a no-op and the last tile could be read before its loads
// land (intermittent replay failure). Fix: vmcnt(8) if T+2<NT else vmcnt(0).
// Wait table: trailing(S): outstanding = 8(S+1, unless S=NT-1) + 8(S+2 if
// staged); need S+1 landed -> vmcnt(8) iff S+2<NT, else vmcnt(0).
// ---------------------------------------------------------------------------
enum { EPI_BF16 = 0, EPI_F32 = 1, EPI_VT = 2, EPI_GELUMUL = 3, EPI_QKV = 4 };

template <int EPI>
__global__ __launch_bounds__(512, 2) void gemm8p(
    const bf16* __restrict__ A, const bf16* __restrict__ Bw,
    void* __restrict__ Cout, const bf16* __restrict__ aux,
    void* __restrict__ C2, void* __restrict__ C3,
    int Ndim, int Kdim) {
  __shared__ __align__(16) char L[131072];  // [buf2][op2][row256][col64] bf16

  const int NT = Kdim >> 6;
  const int NB = gridDim.x;
  const int bid = blockIdx.x;
  // XCD-bijective swizzle (NB%8==0 for all shapes), B-panel-major ordering:
  const int sw = (bid & 7) * (NB >> 3) + (bid >> 3);
  const int m0 = (sw & 15) * 256;  // M = 4096 -> 16 M-tiles, fastest
  const int n0 = (sw >> 4) * 256;

  const int tid = threadIdx.x;
  const int wid = tid >> 6, l = tid & 63;
  const int wm = wid >> 2, wn = wid & 3;
  const int lr = l & 15, lg = l >> 4;

  // --- staging geometry (linear LDS dest, inverse-swizzled global src) ---
  const int rlane = wid * 16 + (l >> 3);        // row within 128-row half
  const int lc8 = (((l & 7) ^ (l >> 3)) << 3);  // swizzled source col (elems)
  const bf16* srcA = A + (size_t)(m0 + rlane) * Kdim + lc8;
  const bf16* srcB = Bw + (size_t)(n0 + rlane) * Kdim + lc8;
  const size_t K128 = (size_t)Kdim << 7;  // 128 rows of elems
  const size_t K8 = (size_t)Kdim << 3;    // 8 rows

  auto STAGE = [&](int op, int rh, int tl) {
    if (tl >= NT) return;
    const bf16* s = (op ? srcB : srcA) + (size_t)rh * K128 + ((size_t)tl << 6);
    char* d = L + ((tl & 1) << 16) + (op << 15) + (rh << 14) + (wid << 11);
    gl_lds16(s, d);
    gl_lds16(s + K8, d + 1024);
  };

  // --- fragment read geometry (swizzled) ---
  const int arow = wm * 128 + lr;
  const int brow = wn * 64 + lr;
  const int swz = lr & 7;
  const int csw0 = ((0 * 4 + lg) ^ swz) << 4;
  const int csw1 = ((1 * 4 + lg) ^ swz) << 4;
  auto LDA = [&](int mi, int kk, int c) {
    return *(const bf16x8_t*)(L + (c << 16) + arow * 128 + mi * 2048 +
                              (kk ? csw1 : csw0));
  };
  auto LDB = [&](int ni, int kk, int c) {
    return *(const bf16x8_t*)(L + (c << 16) + 32768 + brow * 128 + ni * 2048 +
                              (kk ? csw1 : csw0));
  };

  f32x4_t acc[8][4];
  #pragma unroll
  for (int i = 0; i < 8; i++)
    #pragma unroll
    for (int j = 0; j < 4; j++) acc[i][j] = (f32x4_t){0.f, 0.f, 0.f, 0.f};

  bf16x8_t fa[8][2], fb[4][2];

  // prologue: all of tile 0 and tile 1 (16 loads). vmcnt(8) -> tile 0 done.
  STAGE(1, 0, 0); STAGE(1, 1, 0); STAGE(0, 0, 0); STAGE(0, 1, 0);
  STAGE(1, 0, 1); STAGE(1, 1, 1); STAGE(0, 0, 1); STAGE(0, 1, 1);
  asm volatile("s_waitcnt vmcnt(8)" ::: "memory");
  __builtin_amdgcn_s_barrier();
  __builtin_amdgcn_sched_barrier(0);

#define MFMA_Q(MB, NBQ)                                                        \
  _Pragma("unroll") for (int mi = 0; mi < 4; ++mi)                             \
  _Pragma("unroll") for (int ni = 0; ni < 2; ++ni) {                           \
    acc[MB + mi][NBQ + ni] =                                                   \
        mfma16(fa[MB + mi][0], fb[NBQ + ni][0], acc[MB + mi][NBQ + ni]);       \
    acc[MB + mi][NBQ + ni] =                                                   \
        mfma16(fa[MB + mi][1], fb[NBQ + ni][1], acc[MB + mi][NBQ + ni]);       \
  }

#define TILE(T, C)                                                             \
  {                                                                            \
    /* ph0: 12 reads (fa0-3, fb0-1); MFMA Q(0,0) */                            \
    _Pragma("unroll") for (int mi = 0; mi < 4; ++mi) {                         \
      fa[mi][0] = LDA(mi, 0, (C)); fa[mi][1] = LDA(mi, 1, (C));                \
    }                                                                          \
    _Pragma("unroll") for (int ni = 0; ni < 2; ++ni) {                         \
      fb[ni][0] = LDB(ni, 0, (C)); fb[ni][1] = LDB(ni, 1, (C));                \
    }                                                                          \
    __builtin_amdgcn_s_barrier();                                              \
    asm volatile("s_waitcnt lgkmcnt(0)" ::: "memory");                         \
    __builtin_amdgcn_sched_barrier(0);                                         \
    __builtin_amdgcn_s_setprio(1);                                             \
    MFMA_Q(0, 0);                                                              \
    __builtin_amdgcn_s_setprio(0);                                             \
    __builtin_amdgcn_s_barrier();                                              \
    __builtin_amdgcn_sched_barrier(0);                                         \
    /* ph1: 4 reads (fb2-3); MFMA Q(0,2) */                                    \
    _Pragma("unroll") for (int ni = 2; ni < 4; ++ni) {                         \
      fb[ni][0] = LDB(ni, 0, (C)); fb[ni][1] = LDB(ni, 1, (C));                \
    }                                                                          \
    __builtin_amdgcn_s_barrier();                                              \
    asm volatile("s_waitcnt lgkmcnt(0)" ::: "memory");                         \
    __builtin_amdgcn_sched_barrier(0);                                         \
    __builtin_amdgcn_s_setprio(1);                                             \
    MFMA_Q(0, 2);                                                              \
    __builtin_amdgcn_s_setprio(0);                                             \
    __builtin_amdgcn_s_barrier();                                              \
    __builtin_amdgcn_sched_barrier(0);                                         \
    /* ph2: 8 reads (fa4-7) + stage B0,B1(T+2); MFMA Q(4,0) */                 \
    _Pragma("unroll") for (int mi = 4; mi < 8; ++mi) {                         \
      fa[mi][0] = LDA(mi, 0, (C)); fa[mi][1] = LDA(mi, 1, (C));                \
    }                                                                          \
    STAGE(1, 0, (T) + 2);                                                      \
    STAGE(1, 1, (T) + 2);                                                      \
    __builtin_amdgcn_s_barrier();                                              \
    asm volatile("s_waitcnt lgkmcnt(0)" ::: "memory");                         \
    __builtin_amdgcn_sched_barrier(0);                                         \
    __builtin_amdgcn_s_setprio(1);                                             \
    MFMA_Q(4, 0);                                                              \
    __builtin_amdgcn_s_setprio(0);                                             \
    __builtin_amdgcn_s_barrier();                                              \
    __builtin_amdgcn_sched_barrier(0);                                         \
    /* ph3: stage A0,A1(T+2); MFMA Q(4,2); tail-safe vmcnt; barrier */         \
    STAGE(0, 0, (T) + 2);                                                      \
    STAGE(0, 1, (T) + 2);                                                      \
    __builtin_amdgcn_s_barrier();                                              \
    __builtin_amdgcn_s_setprio(1);                                             \
    MFMA_Q(4, 2);                                                              \
    __builtin_amdgcn_s_setprio(0);                                             \
    if ((T) + 2 < NT) {                                                        \
      asm volatile("s_waitcnt vmcnt(8)" ::: "memory");                         \
    } else {                                                                   \
      asm volatile("s_waitcnt vmcnt(0)" ::: "memory");                         \
    }                                                                          \
    __builtin_amdgcn_s_barrier();                                              \
    __builtin_amdgcn_sched_barrier(0);                                         \
  }

  for (int t = 0; t < NT; t += 2) {
    TILE(t, 0);
    TILE(t + 1, 1);
  }
#undef TILE
#undef MFMA_Q

  // Epilogue. C/D layout: col = lane&15, row = (lane>>4)*4 + reg.
  const int row0 = m0 + wm * 128 + lg * 4;
  const int col0 = n0 + wn * 64 + lr;
  #pragma unroll
  for (int mi = 0; mi < 8; mi++) {
    #pragma unroll
    for (int ni = 0; ni < 4; ni++) {
      #pragma unroll
      for (int r = 0; r < 4; r++) {
        const int row = row0 + mi * 16 + r;
        const int col = col0 + ni * 16;
        const float v = acc[mi][ni][r];
        if constexpr (EPI == EPI_BF16) {
          ((bf16*)Cout)[(size_t)row * Ndim + col] = __float2bfloat16(v);
        } else if constexpr (EPI == EPI_F32) {
          ((float*)Cout)[(size_t)row * Ndim + col] = v;
        } else if constexpr (EPI == EPI_VT) {
          // write V transposed: vt[(b*8+kvh)][d][s]
          const int kvh = col >> 8, d = col & 255;
          const int bb = row >> 11, s = row & 2047;
          ((bf16*)Cout)[(((size_t)((bb * 8 + kvh) * 256 + d)) << 11) + s] =
              __float2bfloat16(v);
        } else if constexpr (EPI == EPI_QKV) {
          // cols [0,4096) -> q; [4096,6144) -> k; [6144,8192) -> v^T.
          // Segment boundaries are multiples of 256 -> block-uniform branch.
          if (col < 4096) {
            ((bf16*)Cout)[(size_t)row * 4096 + col] = __float2bfloat16(v);
          } else if (col < 6144) {
            ((bf16*)C2)[(size_t)row * 2048 + (col - 4096)] =
                __float2bfloat16(v);
          } else {
            const int cc = col - 6144;
            const int kvh = cc >> 8, d = cc & 255;
            const int bb = row >> 11, s = row & 2047;
            ((bf16*)C3)[(((size_t)((bb * 8 + kvh) * 256 + d)) << 11) + s] =
                __float2bfloat16(v);
          }
        } else {  // EPI_GELUMUL
          const float g = __bfloat162float(aux[(size_t)row * Ndim + col]);
          const float u = 0.7978845608028654f * (g + 0.044715f * g * g * g);
          const float gl = 0.5f * g * (1.f + tanhf(u));
          ((bf16*)Cout)[(size_t)row * Ndim + col] = __float2bfloat16(gl * v);
        }
      }
    }
  }
  (void)aux; (void)C2; (void)C3;
}

// ---------------------------------------------------------------------------
// RMSNorm of input hidden -> bf16
// ---------------------------------------------------------------------------
__global__ __launch_bounds__(256) void rmsnorm_in(
    const float* __restrict__ x, const float* __restrict__ w,
    bf16* __restrict__ out) {
  const int row = blockIdx.x, t = threadIdx.x;
  const float4* xr = (const float4*)(x + (size_t)row * HID);
  float4 v[4];
  float ss = 0.f;
  #pragma unroll
  for (int j = 0; j < 4; j++) {
    const int idx = t + 256 * j;
    if (idx < HID / 4) {
      v[j] = xr[idx];
      ss += v[j].x * v[j].x + v[j].y * v[j].y + v[j].z * v[j].z + v[j].w * v[j].w;
    }
  }
  ss = block_reduce_sum(ss);
  const float sc = rsqrtf(ss * (1.f / HID) + EPSF);
  const float4* w4 = (const float4*)w;
  bf16* orow = out + (size_t)row * HID;
  #pragma unroll
  for (int j = 0; j < 4; j++) {
    const int idx = t + 256 * j;
    if (idx < HID / 4) {
      const float4 wv = w4[idx];
      ushort4 o;
      o.x = f2bu(v[j].x * sc * (1.f + wv.x));
      o.y = f2bu(v[j].y * sc * (1.f + wv.y));
      o.z = f2bu(v[j].z * sc * (1.f + wv.z));
      o.w = f2bu(v[j].w * sc * (1.f + wv.w));
      *(ushort4*)(orow + idx * 4) = o;
    }
  }
}

// ---------------------------------------------------------------------------
// RoPE in-place on q (16 heads) and k (8 heads), bf16.
// ---------------------------------------------------------------------------
__global__ __launch_bounds__(128) void rope_kernel(
    bf16* __restrict__ q, bf16* __restrict__ k,
    const float* __restrict__ cosb, const float* __restrict__ sinb) {
  const int tok = blockIdx.x;
  const int hs = blockIdx.y;
  const int d = threadIdx.x;  // 0..127
  const int s = tok & (SEQ - 1);
  bf16* ptr = (hs < NHEADS)
                  ? q + (size_t)tok * QOUT + hs * HDIM
                  : k + (size_t)tok * KOUT + (hs - NHEADS) * HDIM;
  const float c = cosb[s * HDIM + d];
  const float sn = sinb[s * HDIM + d];
  const float x0 = __bfloat162float(ptr[d]);
  const float x1 = __bfloat162float(ptr[d + 128]);
  ptr[d] = __float2bfloat16(x0 * c - x1 * sn);
  ptr[d + 128] = __float2bfloat16(x1 * c + x0 * sn);
}

// ---------------------------------------------------------------------------
// Flash attention, sliding window 1024, softcap 50, fixed-base softmax.
// ---------------------------------------------------------------------------
__global__ __launch_bounds__(256) void attn_kernel(
    const bf16* __restrict__ q, const bf16* __restrict__ k,
    const bf16* __restrict__ vt, bf16* __restrict__ out) {
  __shared__ __align__(16) bf16 plds[4][16 * 32];

  const int qt = blockIdx.x, h = blockIdx.y, b = blockIdx.z;
  const int w = threadIdx.x >> 6, l = threadIdx.x & 63;
  const int kvh = h >> 1;
  const int qbase = qt * 64 + w * 16;
  const int lr = l & 15, lg = l >> 4, lk = lg * 8;

  bf16x8_t qf[8];
  const bf16* qrow = q + (size_t)(b * SEQ + qbase + lr) * QOUT + h * HDIM;
  #pragma unroll
  for (int c = 0; c < 8; c++) qf[c] = *(const bf16x8_t*)(qrow + c * 32 + lk);

  f32x4_t acc[16];
  #pragma unroll
  for (int i = 0; i < 16; i++) acc[i] = (f32x4_t){0.f, 0.f, 0.f, 0.f};
  float L[4] = {0.f, 0.f, 0.f, 0.f};

  const bf16* kp = k + (size_t)(b * SEQ) * KOUT + kvh * HDIM;
  const bf16* vp = vt + (size_t)(b * NKVH + kvh) * HDIM * SEQ;
  bf16* pl = &plds[w][0];

  int kstart = qbase - 1023;
  if (kstart < 0) kstart = 0;
  kstart &= ~31;
  const int kend = qbase + 15;

  for (int kb = kstart; kb <= kend; kb += 32) {
    f32x4_t s0 = (f32x4_t){0.f, 0.f, 0.f, 0.f};
    f32x4_t s1 = (f32x4_t){0.f, 0.f, 0.f, 0.f};
    #pragma unroll
    for (int c = 0; c < 8; c++) {
      bf16x8_t k0 = *(const bf16x8_t*)(kp + (size_t)(kb + lr) * KOUT + c * 32 + lk);
      bf16x8_t k1 = *(const bf16x8_t*)(kp + (size_t)(kb + 16 + lr) * KOUT + c * 32 + lk);
      s0 = mfma16(qf[c], k0, s0);
      s1 = mfma16(qf[c], k1, s1);
    }
    float p[8];
    #pragma unroll
    for (int sub = 0; sub < 2; sub++) {
      const int j = kb + sub * 16 + lr;
      #pragma unroll
      for (int r = 0; r < 4; r++) {
        const int i = qbase + lg * 4 + r;
        float sc = (sub ? s1[r] : s0[r]) * 0.0625f;
        sc = 50.f * tanhf(sc * 0.02f);
        const bool ok = (j <= i) && (j > i - 1024);
        p[sub * 4 + r] = ok ? __expf(sc) : 0.f;
      }
    }
    #pragma unroll
    for (int r = 0; r < 4; r++) {
      float ps = p[r] + p[4 + r];
      ps += __shfl_xor(ps, 1, 64);
      ps += __shfl_xor(ps, 2, 64);
      ps += __shfl_xor(ps, 4, 64);
      ps += __shfl_xor(ps, 8, 64);
      L[r] += ps;
    }
    #pragma unroll
    for (int sub = 0; sub < 2; sub++)
      #pragma unroll
      for (int r = 0; r < 4; r++)
        pl[(lg * 4 + r) * 32 + sub * 16 + lr] = __float2bfloat16(p[sub * 4 + r]);
    asm volatile("s_waitcnt lgkmcnt(0)" ::: "memory");
    const bf16x8_t pa = *(const bf16x8_t*)(pl + lr * 32 + lk);
    #pragma unroll
    for (int dt = 0; dt < 16; dt++) {
      bf16x8_t bv = *(const bf16x8_t*)(vp + (size_t)(dt * 16 + lr) * SEQ + kb + lk);
      acc[dt] = mfma16(pa, bv, acc[dt]);
    }
  }

  float rL[4];
  #pragma unroll
  for (int r = 0; r < 4; r++) rL[r] = 1.f / L[r];
  #pragma unroll
  for (int dt = 0; dt < 16; dt++) {
    #pragma unroll
    for (int r = 0; r < 4; r++) {
      const int tok = b * SEQ + qbase + lg * 4 + r;
      out[(size_t)tok * QOUT + h * HDIM + dt * 16 + lr] =
          __float2bfloat16(acc[dt][r] * rL[r]);
    }
  }
}

// ---------------------------------------------------------------------------
// fuse1: h1 = hidden + rmsnorm(attn_proj, w_post); y = bf16(rmsnorm(h1, w_pre))
// ---------------------------------------------------------------------------
__global__ __launch_bounds__(256) void fuse_attn(
    const float* __restrict__ hidden, const float* __restrict__ ap,
    const float* __restrict__ w_post, const float* __restrict__ w_pre,
    float* __restrict__ h1, bf16* __restrict__ y) {
  const int row = blockIdx.x, t = threadIdx.x;
  const float4* ar = (const float4*)(ap + (size_t)row * HID);
  const float4* hr = (const float4*)(hidden + (size_t)row * HID);
  float4 a[4];
  float ss = 0.f;
  #pragma unroll
  for (int j = 0; j < 4; j++) {
    const int idx = t + 256 * j;
    if (idx < HID / 4) {
      a[j] = ar[idx];
      ss += a[j].x * a[j].x + a[j].y * a[j].y + a[j].z * a[j].z + a[j].w * a[j].w;
    }
  }
  ss = block_reduce_sum(ss);
  const float sc = rsqrtf(ss * (1.f / HID) + EPSF);
  const float4* wpo = (const float4*)w_post;
  float4* h1r = (float4*)(h1 + (size_t)row * HID);
  float4 hv[4];
  float ss2 = 0.f;
  #pragma unroll
  for (int j = 0; j < 4; j++) {
    const int idx = t + 256 * j;
    if (idx < HID / 4) {
      const float4 wv = wpo[idx];
      const float4 x = hr[idx];
      hv[j].x = x.x + a[j].x * sc * (1.f + wv.x);
      hv[j].y = x.y + a[j].y * sc * (1.f + wv.y);
      hv[j].z = x.z + a[j].z * sc * (1.f + wv.z);
      hv[j].w = x.w + a[j].w * sc * (1.f + wv.w);
      ss2 += hv[j].x * hv[j].x + hv[j].y * hv[j].y + hv[j].z * hv[j].z + hv[j].w * hv[j].w;
      h1r[idx] = hv[j];
    }
  }
  ss2 = block_reduce_sum(ss2);
  const float sc2 = rsqrtf(ss2 * (1.f / HID) + EPSF);
  const float4* wpr = (const float4*)w_pre;
  bf16* yr = y + (size_t)row * HID;
  #pragma unroll
  for (int j = 0; j < 4; j++) {
    const int idx = t + 256 * j;
    if (idx < HID / 4) {
      const float4 wv = wpr[idx];
      ushort4 o;
      o.x = f2bu(hv[j].x * sc2 * (1.f + wv.x));
      o.y = f2bu(hv[j].y * sc2 * (1.f + wv.y));
      o.z = f2bu(hv[j].z * sc2 * (1.f + wv.z));
      o.w = f2bu(hv[j].w * sc2 * (1.f + wv.w));
      *(ushort4*)(yr + idx * 4) = o;
    }
  }
}

// ---------------------------------------------------------------------------
// fuse2: out = h1 + rmsnorm(mlp, w_post_ff)
// ---------------------------------------------------------------------------
__global__ __launch_bounds__(256) void fuse_out(
    const float* __restrict__ h1, const float* __restrict__ mlp,
    const float* __restrict__ w, float* __restrict__ out) {
  const int row = blockIdx.x, t = threadIdx.x;
  const float4* mr = (const float4*)(mlp + (size_t)row * HID);
  float4 m[4];
  float ss = 0.f;
  #pragma unroll
  for (int j = 0; j < 4; j++) {
    const int idx = t + 256 * j;
    if (idx < HID / 4) {
      m[j] = mr[idx];
      ss += m[j].x * m[j].x + m[j].y * m[j].y + m[j].z * m[j].z + m[j].w * m[j].w;
    }
  }
  ss = block_reduce_sum(ss);
  const float sc = rsqrtf(ss * (1.f / HID) + EPSF);
  const float4* hr = (const float4*)(h1 + (size_t)row * HID);
  const float4* w4 = (const float4*)w;
  float4* orow = (float4*)(out + (size_t)row * HID);
  #pragma unroll
  for (int j = 0; j < 4; j++) {
    const int idx = t + 256 * j;
    if (idx < HID / 4) {
      const float4 wv = w4[idx];
      const float4 x = hr[idx];
      float4 o;
      o.x = x.x + m[j].x * sc * (1.f + wv.x);
      o.y = x.y + m[j].y * sc * (1.f + wv.y);
      o.z = x.z + m[j].z * sc * (1.f + wv.z);
      o.w = x.w + m[j].w * sc * (1.f + wv.w);
      orow[idx] = o;
    }
  }
}

// ---------------------------------------------------------------------------
extern "C" void kernel_launch(void* const* d_in, const int* in_sizes, int n_in,
                              void* d_out, int out_size, void* d_ws,
                              size_t ws_size, hipStream_t stream) {
  const float* hidden = (const float*)d_in[0];
  const float* cosb = (const float*)d_in[1];
  const float* sinb = (const float*)d_in[2];
  const float* Wq = (const float*)d_in[3];
  const float* Wk = (const float*)d_in[4];
  const float* Wv = (const float*)d_in[5];
  const float* Wo = (const float*)d_in[6];
  const float* Wgate = (const float*)d_in[7];
  const float* Wup = (const float*)d_in[8];
  const float* Wdown = (const float*)d_in[9];
  const float* w_in = (const float*)d_in[10];
  const float* w_post_attn = (const float*)d_in[11];
  const float* w_pre_ff = (const float*)d_in[12];
  const float* w_post_ff = (const float*)d_in[13];
  float* out = (float*)d_out;

  (void)in_sizes; (void)n_in; (void)out_size; (void)ws_size;

  const size_t WB = 102760448;  // 14336*3584*2 — bf16 weight scratch
  char* ws = (char*)d_ws;
  bf16* wbuf = (bf16*)ws;
  char* ab = ws + WB;

  // Region 0 (63 MB): xn + q -> attn_proj -> mlp
  bf16* xn = (bf16*)(ab);
  bf16* q = (bf16*)(ab + 29360128);
  float* attn_proj = (float*)(ab);
  float* mlp = (float*)(ab);
  // Region 1 (67 MB): k + vt + attn_out -> h1
  bf16* kbuf = (bf16*)(ab + 62914560);
  bf16* vt = (bf16*)(ab + 62914560 + 16777216);
  bf16* attn_out = (bf16*)(ab + 62914560 + 33554432);
  float* h1 = (float*)(ab + 62914560);
  // Region 2: y
  bf16* y = (bf16*)(ab + 130023424);
  // Region 3: gate (gelu*up written in-place)
  bf16* gate = (bf16*)(ab + 159383552);

  rmsnorm_in<<<MTOK, 256, 0, stream>>>(hidden, w_in, xn);

  // Batched QKV: wbuf rows [0,4096)=Wq, [4096,6144)=Wk, [6144,8192)=Wv
  cvt_w<<<4096, 256, 0, stream>>>(Wq, wbuf, QOUT * HID);
  cvt_w<<<2048, 256, 0, stream>>>(Wk, wbuf + (size_t)QOUT * HID, KOUT * HID);
  cvt_w<<<2048, 256, 0, stream>>>(Wv, wbuf + (size_t)(QOUT + KOUT) * HID,
                                  KOUT * HID);
  gemm8p<EPI_QKV><<<(8192 / 256) * 16, 512, 0, stream>>>(
      xn, wbuf, q, nullptr, kbuf, vt, 8192, HID);
  rope_kernel<<<dim3(MTOK, NHEADS + NKVH), 128, 0, stream>>>(q, kbuf, cosb, sinb);
  attn_kernel<<<dim3(SEQ / 64, NHEADS, NBATCH), 256, 0, stream>>>(
      q, kbuf, vt, attn_out);
  cvt_w<<<4096, 256, 0, stream>>>(Wo, wbuf, HID * QOUT);
  gemm8p<EPI_F32><<<(HID / 256) * 16, 512, 0, stream>>>(
      attn_out, wbuf, attn_proj, nullptr, nullptr, nullptr, HID, QOUT);
  fuse_attn<<<MTOK, 256, 0, stream>>>(hidden, attn_proj, w_post_attn,
                                      w_pre_ff, h1, y);
  cvt_w<<<4096, 256, 0, stream>>>(Wgate, wbuf, INTERD * HID);
  gemm8p<EPI_BF16><<<(INTERD / 256) * 16, 512, 0, stream>>>(
      y, wbuf, gate, nullptr, nullptr, nullptr, INTERD, HID);
  cvt_w<<<4096, 256, 0, stream>>>(Wup, wbuf, INTERD * HID);
  gemm8p<EPI_GELUMUL><<<(INTERD / 256) * 16, 512, 0, stream>>>(
      y, wbuf, gate, gate, nullptr, nullptr, INTERD, HID);
  cvt_w<<<4096, 256, 0, stream>>>(Wdown, wbuf, HID * INTERD);
  gemm8p<EPI_F32><<<(HID / 256) * 16, 512, 0, stream>>>(
      gate, wbuf, mlp, nullptr, nullptr, nullptr, HID, INTERD);

  fuse_out<<<MTOK, 256, 0, stream>>>(h1, mlp, w_post_ff, out);
}

// Round 7
// 2734.793 us; speedup vs baseline: 1.0193x; 1.0193x over previous
//
#include <hip/hip_runtime.h>
#include <hip/hip_bf16.h>

typedef __hip_bfloat16 bf16;
typedef __bf16 bf16x8_t __attribute__((ext_vector_type(8)));
typedef float f32x4_t __attribute__((ext_vector_type(4)));
typedef unsigned short u16x8_t __attribute__((ext_vector_type(8)));

#define HID 3584
#define SEQ 2048
#define NBATCH 2
#define MTOK 4096
#define NHEADS 16
#define NKVH 8
#define HDIM 256
#define QOUT 4096
#define KOUT 2048
#define INTERD 14336
#define EPSF 1e-6f

static __device__ __forceinline__ unsigned short f2bu(float f) {
  union { bf16 b; unsigned short u; } cv;
  cv.b = __float2bfloat16(f);
  return cv.u;
}

static __device__ __forceinline__ f32x4_t mfma16(bf16x8_t a, bf16x8_t b, f32x4_t c) {
  return __builtin_amdgcn_mfma_f32_16x16x32_bf16(a, b, c, 0, 0, 0);
}

static __device__ __forceinline__ void gl_lds16(const void* g, void* l) {
  __builtin_amdgcn_global_load_lds((__attribute__((address_space(1))) void*)g,
                                   (__attribute__((address_space(3))) void*)l,
                                   16, 0, 0);
}

static __device__ __forceinline__ float block_reduce_sum(float v) {
  __shared__ float buf[4];
  #pragma unroll
  for (int m = 1; m < 64; m <<= 1) v += __shfl_xor(v, m, 64);
  __syncthreads();
  if ((threadIdx.x & 63) == 0) buf[threadIdx.x >> 6] = v;
  __syncthreads();
  return buf[0] + buf[1] + buf[2] + buf[3];
}

// ---------------------------------------------------------------------------
// weight convert: f32 -> bf16
// ---------------------------------------------------------------------------
__global__ __launch_bounds__(256) void cvt_w(
    const float* __restrict__ src, bf16* __restrict__ dst, int n) {
  const int stride = gridDim.x * 256 * 8;
  for (int i = (blockIdx.x * 256 + threadIdx.x) * 8; i < n; i += stride) {
    const float4 a = *(const float4*)(src + i);
    const float4 b = *(const float4*)(src + i + 4);
    u16x8_t o;
    o[0] = f2bu(a.x); o[1] = f2bu(a.y); o[2] = f2bu(a.z); o[3] = f2bu(a.w);
    o[4] = f2bu(b.x); o[5] = f2bu(b.y); o[6] = f2bu(b.z); o[7] = f2bu(b.w);
    *(u16x8_t*)(dst + i) = o;
  }
}

// ---------------------------------------------------------------------------
// 8-phase 256x256 GEMM. R7: pre-MFMA barriers REMOVED (only post-MFMA +
// trailing publish = 4 barriers/tile). Rationale: reads are self-ordered by
// per-wave lgkmcnt(0); each stage that overwrites a buf-C region is issued
// after the post-MFMA barrier that proves all waves' reads of that region
// completed (each wave's reads complete before its own MFMA). Waves may now
// desync within a phase -> one wave's ds_reads overlap another's MFMA
// (the T5/m218 role-split mechanism my lockstep barriers were blocking).
// mshift: log2(#M-tiles); m0=(sw&(2^mshift-1))*256, n0=(sw>>mshift)*256.
// ---------------------------------------------------------------------------
enum { EPI_BF16 = 0, EPI_F32 = 1, EPI_GELUMUL = 2, EPI_QK = 3, EPI_VSW = 4 };

template <int EPI>
__global__ __launch_bounds__(512, 2) void gemm8p(
    const bf16* __restrict__ A, const bf16* __restrict__ Bw,
    void* __restrict__ Cout, const bf16* __restrict__ aux,
    void* __restrict__ C2, int Ndim, int Kdim, int mshift) {
  __shared__ __align__(16) char L[131072];  // [buf2][op2][row256][col64] bf16

  const int NT = Kdim >> 6;
  const int NB = gridDim.x;
  const int bid = blockIdx.x;
  // XCD-bijective swizzle (NB%8==0 for all shapes), B-panel-major ordering:
  const int sw = (bid & 7) * (NB >> 3) + (bid >> 3);
  const int m0 = (sw & ((1 << mshift) - 1)) << 8;
  const int n0 = (sw >> mshift) << 8;

  const int tid = threadIdx.x;
  const int wid = tid >> 6, l = tid & 63;
  const int wm = wid >> 2, wn = wid & 3;
  const int lr = l & 15, lg = l >> 4;

  // --- staging geometry (linear LDS dest, inverse-swizzled global src) ---
  const int rlane = wid * 16 + (l >> 3);        // row within 128-row half
  const int lc8 = (((l & 7) ^ (l >> 3)) << 3);  // swizzled source col (elems)
  const bf16* srcA = A + (size_t)(m0 + rlane) * Kdim + lc8;
  const bf16* srcB = Bw + (size_t)(n0 + rlane) * Kdim + lc8;
  const size_t K128 = (size_t)Kdim << 7;  // 128 rows of elems
  const size_t K8 = (size_t)Kdim << 3;    // 8 rows

  auto STAGE = [&](int op, int rh, int tl) {
    if (tl >= NT) return;
    const bf16* s = (op ? srcB : srcA) + (size_t)rh * K128 + ((size_t)tl << 6);
    char* d = L + ((tl & 1) << 16) + (op << 15) + (rh << 14) + (wid << 11);
    gl_lds16(s, d);
    gl_lds16(s + K8, d + 1024);
  };

  // --- fragment read geometry (swizzled) ---
  const int arow = wm * 128 + lr;
  const int brow = wn * 64 + lr;
  const int swz = lr & 7;
  const int csw0 = ((0 * 4 + lg) ^ swz) << 4;
  const int csw1 = ((1 * 4 + lg) ^ swz) << 4;
  auto LDA = [&](int mi, int kk, int c) {
    return *(const bf16x8_t*)(L + (c << 16) + arow * 128 + mi * 2048 +
                              (kk ? csw1 : csw0));
  };
  auto LDB = [&](int ni, int kk, int c) {
    return *(const bf16x8_t*)(L + (c << 16) + 32768 + brow * 128 + ni * 2048 +
                              (kk ? csw1 : csw0));
  };

  f32x4_t acc[8][4];
  #pragma unroll
  for (int i = 0; i < 8; i++)
    #pragma unroll
    for (int j = 0; j < 4; j++) acc[i][j] = (f32x4_t){0.f, 0.f, 0.f, 0.f};

  bf16x8_t fa[8][2], fb[4][2];

  // prologue: all of tile 0 and tile 1 (16 loads). vmcnt(8) -> tile 0 done.
  STAGE(1, 0, 0); STAGE(1, 1, 0); STAGE(0, 0, 0); STAGE(0, 1, 0);
  STAGE(1, 0, 1); STAGE(1, 1, 1); STAGE(0, 0, 1); STAGE(0, 1, 1);
  asm volatile("s_waitcnt vmcnt(8)" ::: "memory");
  __builtin_amdgcn_s_barrier();
  __builtin_amdgcn_sched_barrier(0);

#define MFMA_Q(MB, NBQ)                                                        \
  _Pragma("unroll") for (int mi = 0; mi < 4; ++mi)                             \
  _Pragma("unroll") for (int ni = 0; ni < 2; ++ni) {                           \
    acc[MB + mi][NBQ + ni] =                                                   \
        mfma16(fa[MB + mi][0], fb[NBQ + ni][0], acc[MB + mi][NBQ + ni]);       \
    acc[MB + mi][NBQ + ni] =                                                   \
        mfma16(fa[MB + mi][1], fb[NBQ + ni][1], acc[MB + mi][NBQ + ni]);       \
  }

#define TILE(T, C)                                                             \
  {                                                                            \
    /* ph0: 12 reads (fa0-3, fb0-1); lgkm self-wait; MFMA Q(0,0) */            \
    _Pragma("unroll") for (int mi = 0; mi < 4; ++mi) {                         \
      fa[mi][0] = LDA(mi, 0, (C)); fa[mi][1] = LDA(mi, 1, (C));                \
    }                                                                          \
    _Pragma("unroll") for (int ni = 0; ni < 2; ++ni) {                         \
      fb[ni][0] = LDB(ni, 0, (C)); fb[ni][1] = LDB(ni, 1, (C));                \
    }                                                                          \
    asm volatile("s_waitcnt lgkmcnt(0)" ::: "memory");                         \
    __builtin_amdgcn_sched_barrier(0);                                         \
    __builtin_amdgcn_s_setprio(1);                                             \
    MFMA_Q(0, 0);                                                              \
    __builtin_amdgcn_s_setprio(0);                                             \
    __builtin_amdgcn_s_barrier();                                              \
    /* ph1: 4 reads (fb2-3); MFMA Q(0,2); post-barrier => all B-reads done */  \
    _Pragma("unroll") for (int ni = 2; ni < 4; ++ni) {                         \
      fb[ni][0] = LDB(ni, 0, (C)); fb[ni][1] = LDB(ni, 1, (C));                \
    }                                                                          \
    asm volatile("s_waitcnt lgkmcnt(0)" ::: "memory");                         \
    __builtin_amdgcn_sched_barrier(0);                                         \
    __builtin_amdgcn_s_setprio(1);                                             \
    MFMA_Q(0, 2);                                                              \
    __builtin_amdgcn_s_setprio(0);                                             \
    __builtin_amdgcn_s_barrier();                                              \
    /* ph2: stage B0,B1(T+2) (B region dead); 8 reads (fa4-7); MFMA Q(4,0); */ \
    /* post-barrier => all A-reads done */                                     \
    STAGE(1, 0, (T) + 2);                                                      \
    STAGE(1, 1, (T) + 2);                                                      \
    _Pragma("unroll") for (int mi = 4; mi < 8; ++mi) {                         \
      fa[mi][0] = LDA(mi, 0, (C)); fa[mi][1] = LDA(mi, 1, (C));                \
    }                                                                          \
    asm volatile("s_waitcnt lgkmcnt(0)" ::: "memory");                         \
    __builtin_amdgcn_sched_barrier(0);                                         \
    __builtin_amdgcn_s_setprio(1);                                             \
    MFMA_Q(4, 0);                                                              \
    __builtin_amdgcn_s_setprio(0);                                             \
    __builtin_amdgcn_s_barrier();                                              \
    /* ph3: stage A0,A1(T+2) (A region dead); MFMA Q(4,2) from regs;         */\
    /* tail-aware vmcnt; trailing barrier publishes tile T+1 */                \
    STAGE(0, 0, (T) + 2);                                                      \
    STAGE(0, 1, (T) + 2);                                                      \
    __builtin_amdgcn_s_setprio(1);                                             \
    MFMA_Q(4, 2);                                                              \
    __builtin_amdgcn_s_setprio(0);                                             \
    if ((T) + 2 < NT) {                                                        \
      asm volatile("s_waitcnt vmcnt(8)" ::: "memory");                         \
    } else {                                                                   \
      asm volatile("s_waitcnt vmcnt(0)" ::: "memory");                         \
    }                                                                          \
    __builtin_amdgcn_s_barrier();                                              \
    __builtin_amdgcn_sched_barrier(0);                                         \
  }

  for (int t = 0; t < NT; t += 2) {
    TILE(t, 0);
    TILE(t + 1, 1);
  }
#undef TILE
#undef MFMA_Q

  // Epilogue. C/D layout: col = lane&15, row = (lane>>4)*4 + reg.
  const int row0 = m0 + wm * 128 + lg * 4;
  const int col0 = n0 + wn * 64 + lr;
  #pragma unroll
  for (int mi = 0; mi < 8; mi++) {
    #pragma unroll
    for (int ni = 0; ni < 4; ni++) {
      #pragma unroll
      for (int r = 0; r < 4; r++) {
        const int row = row0 + mi * 16 + r;
        const int col = col0 + ni * 16;
        const float v = acc[mi][ni][r];
        if constexpr (EPI == EPI_BF16) {
          ((bf16*)Cout)[(size_t)row * Ndim + col] = __float2bfloat16(v);
        } else if constexpr (EPI == EPI_F32) {
          ((float*)Cout)[(size_t)row * Ndim + col] = v;
        } else if constexpr (EPI == EPI_QK) {
          // cols [0,4096) -> q (row-major); [4096,6144) -> k (row-major).
          // Boundary multiple of 256 -> block-uniform branch.
          if (col < 4096) {
            ((bf16*)Cout)[(size_t)row * 4096 + col] = __float2bfloat16(v);
          } else {
            ((bf16*)C2)[(size_t)row * 2048 + (col - 4096)] =
                __float2bfloat16(v);
          }
        } else if constexpr (EPI == EPI_VSW) {
          // swapped V GEMM: row = kv-dim (kvh*256+d), col = token (b*2048+s).
          // vt[(b*8+kvh)*256+d][s] -- consecutive lr = consecutive s ->
          // coalesced 32B runs.
          const int bb = col >> 11, s = col & 2047;
          ((bf16*)Cout)[(((size_t)((bb * 8 + (row >> 8)) * 256 + (row & 255)))
                         << 11) + s] = __float2bfloat16(v);
        } else {  // EPI_GELUMUL
          const float g = __bfloat162float(aux[(size_t)row * Ndim + col]);
          const float u = 0.7978845608028654f * (g + 0.044715f * g * g * g);
          const float gl = 0.5f * g * (1.f + tanhf(u));
          ((bf16*)Cout)[(size_t)row * Ndim + col] = __float2bfloat16(gl * v);
        }
      }
    }
  }
  (void)aux; (void)C2;
}

// ---------------------------------------------------------------------------
// RMSNorm of input hidden -> bf16
// ---------------------------------------------------------------------------
__global__ __launch_bounds__(256) void rmsnorm_in(
    const float* __restrict__ x, const float* __restrict__ w,
    bf16* __restrict__ out) {
  const int row = blockIdx.x, t = threadIdx.x;
  const float4* xr = (const float4*)(x + (size_t)row * HID);
  float4 v[4];
  float ss = 0.f;
  #pragma unroll
  for (int j = 0; j < 4; j++) {
    const int idx = t + 256 * j;
    if (idx < HID / 4) {
      v[j] = xr[idx];
      ss += v[j].x * v[j].x + v[j].y * v[j].y + v[j].z * v[j].z + v[j].w * v[j].w;
    }
  }
  ss = block_reduce_sum(ss);
  const float sc = rsqrtf(ss * (1.f / HID) + EPSF);
  const float4* w4 = (const float4*)w;
  bf16* orow = out + (size_t)row * HID;
  #pragma unroll
  for (int j = 0; j < 4; j++) {
    const int idx = t + 256 * j;
    if (idx < HID / 4) {
      const float4 wv = w4[idx];
      ushort4 o;
      o.x = f2bu(v[j].x * sc * (1.f + wv.x));
      o.y = f2bu(v[j].y * sc * (1.f + wv.y));
      o.z = f2bu(v[j].z * sc * (1.f + wv.z));
      o.w = f2bu(v[j].w * sc * (1.f + wv.w));
      *(ushort4*)(orow + idx * 4) = o;
    }
  }
}

// ---------------------------------------------------------------------------
// RoPE in-place on q (16 heads) and k (8 heads), bf16.
// ---------------------------------------------------------------------------
__global__ __launch_bounds__(128) void rope_kernel(
    bf16* __restrict__ q, bf16* __restrict__ k,
    const float* __restrict__ cosb, const float* __restrict__ sinb) {
  const int tok = blockIdx.x;
  const int hs = blockIdx.y;
  const int d = threadIdx.x;  // 0..127
  const int s = tok & (SEQ - 1);
  bf16* ptr = (hs < NHEADS)
                  ? q + (size_t)tok * QOUT + hs * HDIM
                  : k + (size_t)tok * KOUT + (hs - NHEADS) * HDIM;
  const float c = cosb[s * HDIM + d];
  const float sn = sinb[s * HDIM + d];
  const float x0 = __bfloat162float(ptr[d]);
  const float x1 = __bfloat162float(ptr[d + 128]);
  ptr[d] = __float2bfloat16(x0 * c - x1 * sn);
  ptr[d + 128] = __float2bfloat16(x1 * c + x0 * sn);
}

// ---------------------------------------------------------------------------
// Flash attention, sliding window 1024, softcap 50, fixed-base softmax.
// ---------------------------------------------------------------------------
__global__ __launch_bounds__(256) void attn_kernel(
    const bf16* __restrict__ q, const bf16* __restrict__ k,
    const bf16* __restrict__ vt, bf16* __restrict__ out) {
  __shared__ __align__(16) bf16 plds[4][16 * 32];

  const int qt = blockIdx.x, h = blockIdx.y, b = blockIdx.z;
  const int w = threadIdx.x >> 6, l = threadIdx.x & 63;
  const int kvh = h >> 1;
  const int qbase = qt * 64 + w * 16;
  const int lr = l & 15, lg = l >> 4, lk = lg * 8;

  bf16x8_t qf[8];
  const bf16* qrow = q + (size_t)(b * SEQ + qbase + lr) * QOUT + h * HDIM;
  #pragma unroll
  for (int c = 0; c < 8; c++) qf[c] = *(const bf16x8_t*)(qrow + c * 32 + lk);

  f32x4_t acc[16];
  #pragma unroll
  for (int i = 0; i < 16; i++) acc[i] = (f32x4_t){0.f, 0.f, 0.f, 0.f};
  float L[4] = {0.f, 0.f, 0.f, 0.f};

  const bf16* kp = k + (size_t)(b * SEQ) * KOUT + kvh * HDIM;
  const bf16* vp = vt + (size_t)(b * NKVH + kvh) * HDIM * SEQ;
  bf16* pl = &plds[w][0];

  int kstart = qbase - 1023;
  if (kstart < 0) kstart = 0;
  kstart &= ~31;
  const int kend = qbase + 15;

  for (int kb = kstart; kb <= kend; kb += 32) {
    f32x4_t s0 = (f32x4_t){0.f, 0.f, 0.f, 0.f};
    f32x4_t s1 = (f32x4_t){0.f, 0.f, 0.f, 0.f};
    #pragma unroll
    for (int c = 0; c < 8; c++) {
      bf16x8_t k0 = *(const bf16x8_t*)(kp + (size_t)(kb + lr) * KOUT + c * 32 + lk);
      bf16x8_t k1 = *(const bf16x8_t*)(kp + (size_t)(kb + 16 + lr) * KOUT + c * 32 + lk);
      s0 = mfma16(qf[c], k0, s0);
      s1 = mfma16(qf[c], k1, s1);
    }
    float p[8];
    #pragma unroll
    for (int sub = 0; sub < 2; sub++) {
      const int j = kb + sub * 16 + lr;
      #pragma unroll
      for (int r = 0; r < 4; r++) {
        const int i = qbase + lg * 4 + r;
        float sc = (sub ? s1[r] : s0[r]) * 0.0625f;
        sc = 50.f * tanhf(sc * 0.02f);
        const bool ok = (j <= i) && (j > i - 1024);
        p[sub * 4 + r] = ok ? __expf(sc) : 0.f;
      }
    }
    #pragma unroll
    for (int r = 0; r < 4; r++) {
      float ps = p[r] + p[4 + r];
      ps += __shfl_xor(ps, 1, 64);
      ps += __shfl_xor(ps, 2, 64);
      ps += __shfl_xor(ps, 4, 64);
      ps += __shfl_xor(ps, 8, 64);
      L[r] += ps;
    }
    #pragma unroll
    for (int sub = 0; sub < 2; sub++)
      #pragma unroll
      for (int r = 0; r < 4; r++)
        pl[(lg * 4 + r) * 32 + sub * 16 + lr] = __float2bfloat16(p[sub * 4 + r]);
    asm volatile("s_waitcnt lgkmcnt(0)" ::: "memory");
    const bf16x8_t pa = *(const bf16x8_t*)(pl + lr * 32 + lk);
    #pragma unroll
    for (int dt = 0; dt < 16; dt++) {
      bf16x8_t bv = *(const bf16x8_t*)(vp + (size_t)(dt * 16 + lr) * SEQ + kb + lk);
      acc[dt] = mfma16(pa, bv, acc[dt]);
    }
  }

  float rL[4];
  #pragma unroll
  for (int r = 0; r < 4; r++) rL[r] = 1.f / L[r];
  #pragma unroll
  for (int dt = 0; dt < 16; dt++) {
    #pragma unroll
    for (int r = 0; r < 4; r++) {
      const int tok = b * SEQ + qbase + lg * 4 + r;
      out[(size_t)tok * QOUT + h * HDIM + dt * 16 + lr] =
          __float2bfloat16(acc[dt][r] * rL[r]);
    }
  }
}

// ---------------------------------------------------------------------------
// fuse1: h1 = hidden + rmsnorm(attn_proj, w_post); y = bf16(rmsnorm(h1, w_pre))
// ---------------------------------------------------------------------------
__global__ __launch_bounds__(256) void fuse_attn(
    const float* __restrict__ hidden, const float* __restrict__ ap,
    const float* __restrict__ w_post, const float* __restrict__ w_pre,
    float* __restrict__ h1, bf16* __restrict__ y) {
  const int row = blockIdx.x, t = threadIdx.x;
  const float4* ar = (const float4*)(ap + (size_t)row * HID);
  const float4* hr = (const float4*)(hidden + (size_t)row * HID);
  float4 a[4];
  float ss = 0.f;
  #pragma unroll
  for (int j = 0; j < 4; j++) {
    const int idx = t + 256 * j;
    if (idx < HID / 4) {
      a[j] = ar[idx];
      ss += a[j].x * a[j].x + a[j].y * a[j].y + a[j].z * a[j].z + a[j].w * a[j].w;
    }
  }
  ss = block_reduce_sum(ss);
  const float sc = rsqrtf(ss * (1.f / HID) + EPSF);
  const float4* wpo = (const float4*)w_post;
  float4* h1r = (float4*)(h1 + (size_t)row * HID);
  float4 hv[4];
  float ss2 = 0.f;
  #pragma unroll
  for (int j = 0; j < 4; j++) {
    const int idx = t + 256 * j;
    if (idx < HID / 4) {
      const float4 wv = wpo[idx];
      const float4 x = hr[idx];
      hv[j].x = x.x + a[j].x * sc * (1.f + wv.x);
      hv[j].y = x.y + a[j].y * sc * (1.f + wv.y);
      hv[j].z = x.z + a[j].z * sc * (1.f + wv.z);
      hv[j].w = x.w + a[j].w * sc * (1.f + wv.w);
      ss2 += hv[j].x * hv[j].x + hv[j].y * hv[j].y + hv[j].z * hv[j].z + hv[j].w * hv[j].w;
      h1r[idx] = hv[j];
    }
  }
  ss2 = block_reduce_sum(ss2);
  const float sc2 = rsqrtf(ss2 * (1.f / HID) + EPSF);
  const float4* wpr = (const float4*)w_pre;
  bf16* yr = y + (size_t)row * HID;
  #pragma unroll
  for (int j = 0; j < 4; j++) {
    const int idx = t + 256 * j;
    if (idx < HID / 4) {
      const float4 wv = wpr[idx];
      ushort4 o;
      o.x = f2bu(hv[j].x * sc2 * (1.f + wv.x));
      o.y = f2bu(hv[j].y * sc2 * (1.f + wv.y));
      o.z = f2bu(hv[j].z * sc2 * (1.f + wv.z));
      o.w = f2bu(hv[j].w * sc2 * (1.f + wv.w));
      *(ushort4*)(yr + idx * 4) = o;
    }
  }
}

// ---------------------------------------------------------------------------
// fuse2: out = h1 + rmsnorm(mlp, w_post_ff)
// ---------------------------------------------------------------------------
__global__ __launch_bounds__(256) void fuse_out(
    const float* __restrict__ h1, const float* __restrict__ mlp,
    const float* __restrict__ w, float* __restrict__ out) {
  const int row = blockIdx.x, t = threadIdx.x;
  const float4* mr = (const float4*)(mlp + (size_t)row * HID);
  float4 m[4];
  float ss = 0.f;
  #pragma unroll
  for (int j = 0; j < 4; j++) {
    const int idx = t + 256 * j;
    if (idx < HID / 4) {
      m[j] = mr[idx];
      ss += m[j].x * m[j].x + m[j].y * m[j].y + m[j].z * m[j].z + m[j].w * m[j].w;
    }
  }
  ss = block_reduce_sum(ss);
  const float sc = rsqrtf(ss * (1.f / HID) + EPSF);
  const float4* hr = (const float4*)(h1 + (size_t)row * HID);
  const float4* w4 = (const float4*)w;
  float4* orow = (float4*)(out + (size_t)row * HID);
  #pragma unroll
  for (int j = 0; j < 4; j++) {
    const int idx = t + 256 * j;
    if (idx < HID / 4) {
      const float4 wv = w4[idx];
      const float4 x = hr[idx];
      float4 o;
      o.x = x.x + m[j].x * sc * (1.f + wv.x);
      o.y = x.y + m[j].y * sc * (1.f + wv.y);
      o.z = x.z + m[j].z * sc * (1.f + wv.z);
      o.w = x.w + m[j].w * sc * (1.f + wv.w);
      orow[idx] = o;
    }
  }
}

// ---------------------------------------------------------------------------
extern "C" void kernel_launch(void* const* d_in, const int* in_sizes, int n_in,
                              void* d_out, int out_size, void* d_ws,
                              size_t ws_size, hipStream_t stream) {
  const float* hidden = (const float*)d_in[0];
  const float* cosb = (const float*)d_in[1];
  const float* sinb = (const float*)d_in[2];
  const float* Wq = (const float*)d_in[3];
  const float* Wk = (const float*)d_in[4];
  const float* Wv = (const float*)d_in[5];
  const float* Wo = (const float*)d_in[6];
  const float* Wgate = (const float*)d_in[7];
  const float* Wup = (const float*)d_in[8];
  const float* Wdown = (const float*)d_in[9];
  const float* w_in = (const float*)d_in[10];
  const float* w_post_attn = (const float*)d_in[11];
  const float* w_pre_ff = (const float*)d_in[12];
  const float* w_post_ff = (const float*)d_in[13];
  float* out = (float*)d_out;

  (void)in_sizes; (void)n_in; (void)out_size; (void)ws_size;

  const size_t WB = 102760448;  // 14336*3584*2 — bf16 weight scratch
  char* ws = (char*)d_ws;
  bf16* wbuf = (bf16*)ws;
  char* ab = ws + WB;

  // Region 0 (63 MB): xn + q -> attn_proj -> mlp
  bf16* xn = (bf16*)(ab);
  bf16* q = (bf16*)(ab + 29360128);
  float* attn_proj = (float*)(ab);
  float* mlp = (float*)(ab);
  // Region 1 (67 MB): k + vt + attn_out -> h1
  bf16* kbuf = (bf16*)(ab + 62914560);
  bf16* vt = (bf16*)(ab + 62914560 + 16777216);
  bf16* attn_out = (bf16*)(ab + 62914560 + 33554432);
  float* h1 = (float*)(ab + 62914560);
  // Region 2: y
  bf16* y = (bf16*)(ab + 130023424);
  // Region 3: gate (gelu*up written in-place)
  bf16* gate = (bf16*)(ab + 159383552);

  rmsnorm_in<<<MTOK, 256, 0, stream>>>(hidden, w_in, xn);

  // wbuf rows [0,4096)=Wq, [4096,6144)=Wk, [6144,8192)=Wv
  cvt_w<<<4096, 256, 0, stream>>>(Wq, wbuf, QOUT * HID);
  cvt_w<<<2048, 256, 0, stream>>>(Wk, wbuf + (size_t)QOUT * HID, KOUT * HID);
  cvt_w<<<2048, 256, 0, stream>>>(Wv, wbuf + (size_t)(QOUT + KOUT) * HID,
                                  KOUT * HID);
  // QK: N=6144 (q rows + k rows), coalesced row-major outputs.
  gemm8p<EPI_QK><<<(6144 / 256) * 16, 512, 0, stream>>>(
      xn, wbuf, q, nullptr, kbuf, 6144, HID, 4);
  // V swapped: vt[kv][tok] = Wv[kv][h] * xn[tok][h]^T; M=2048 (mshift=3).
  gemm8p<EPI_VSW><<<(4096 / 256) * 8, 512, 0, stream>>>(
      wbuf + (size_t)(QOUT + KOUT) * HID, xn, vt, nullptr, nullptr,
      4096, HID, 3);
  rope_kernel<<<dim3(MTOK, NHEADS + NKVH), 128, 0, stream>>>(q, kbuf, cosb, sinb);
  attn_kernel<<<dim3(SEQ / 64, NHEADS, NBATCH), 256, 0, stream>>>(
      q, kbuf, vt, attn_out);
  cvt_w<<<4096, 256, 0, stream>>>(Wo, wbuf, HID * QOUT);
  gemm8p<EPI_F32><<<(HID / 256) * 16, 512, 0, stream>>>(
      attn_out, wbuf, attn_proj, nullptr, nullptr, HID, QOUT, 4);
  fuse_attn<<<MTOK, 256, 0, stream>>>(hidden, attn_proj, w_post_attn,
                                      w_pre_ff, h1, y);
  cvt_w<<<4096, 256, 0, stream>>>(Wgate, wbuf, INTERD * HID);
  gemm8p<EPI_BF16><<<(INTERD / 256) * 16, 512, 0, stream>>>(
      y, wbuf, gate, nullptr, nullptr, INTERD, HID, 4);
  cvt_w<<<4096, 256, 0, stream>>>(Wup, wbuf, INTERD * HID);
  gemm8p<EPI_GELUMUL><<<(INTERD / 256) * 16, 512, 0, stream>>>(
      y, wbuf, gate, gate, nullptr, INTERD, HID, 4);
  cvt_w<<<4096, 256, 0, stream>>>(Wdown, wbuf, HID * INTERD);
  gemm8p<EPI_F32><<<(HID / 256) * 16, 512, 0, stream>>>(
      gate, wbuf, mlp, nullptr, nullptr, HID, INTERD, 4);

  fuse_out<<<MTOK, 256, 0, stream>>>(h1, mlp, w_post_ff, out);
}

// Round 8
// 2674.245 us; speedup vs baseline: 1.0423x; 1.0226x over previous
//
#include <hip/hip_runtime.h>
#include <hip/hip_bf16.h>

typedef __hip_bfloat16 bf16;
typedef __bf16 bf16x8_t __attribute__((ext_vector_type(8)));
typedef float f32x4_t __attribute__((ext_vector_type(4)));
typedef unsigned short u16x8_t __attribute__((ext_vector_type(8)));

#define HID 3584
#define SEQ 2048
#define NBATCH 2
#define MTOK 4096
#define NHEADS 16
#define NKVH 8
#define HDIM 256
#define QOUT 4096
#define KOUT 2048
#define INTERD 14336
#define EPSF 1e-6f

static __device__ __forceinline__ unsigned short f2bu(float f) {
  union { bf16 b; unsigned short u; } cv;
  cv.b = __float2bfloat16(f);
  return cv.u;
}

static __device__ __forceinline__ f32x4_t mfma16(bf16x8_t a, bf16x8_t b, f32x4_t c) {
  return __builtin_amdgcn_mfma_f32_16x16x32_bf16(a, b, c, 0, 0, 0);
}

static __device__ __forceinline__ void gl_lds16(const void* g, void* l) {
  __builtin_amdgcn_global_load_lds((__attribute__((address_space(1))) void*)g,
                                   (__attribute__((address_space(3))) void*)l,
                                   16, 0, 0);
}

static __device__ __forceinline__ float block_reduce_sum(float v) {
  __shared__ float buf[4];
  #pragma unroll
  for (int m = 1; m < 64; m <<= 1) v += __shfl_xor(v, m, 64);
  __syncthreads();
  if ((threadIdx.x & 63) == 0) buf[threadIdx.x >> 6] = v;
  __syncthreads();
  return buf[0] + buf[1] + buf[2] + buf[3];
}

// ---------------------------------------------------------------------------
// weight convert: f32 -> bf16
// ---------------------------------------------------------------------------
__global__ __launch_bounds__(256) void cvt_w(
    const float* __restrict__ src, bf16* __restrict__ dst, int n) {
  const int stride = gridDim.x * 256 * 8;
  for (int i = (blockIdx.x * 256 + threadIdx.x) * 8; i < n; i += stride) {
    const float4 a = *(const float4*)(src + i);
    const float4 b = *(const float4*)(src + i + 4);
    u16x8_t o;
    o[0] = f2bu(a.x); o[1] = f2bu(a.y); o[2] = f2bu(a.z); o[3] = f2bu(a.w);
    o[4] = f2bu(b.x); o[5] = f2bu(b.y); o[6] = f2bu(b.z); o[7] = f2bu(b.w);
    *(u16x8_t*)(dst + i) = o;
  }
}

// ---------------------------------------------------------------------------
// 8-phase 256x256 GEMM. R8: ALL sched_barrier(0) removed from the K-loop
// (m141: order-pinning defeats the compiler's fine-grained lgkmcnt scheduling,
// 510 vs 874 TF). ds_reads are compiler-visible C++ loads, so MFMA<->read
// ordering is protected by SSA data-deps; the asm lgkmcnt(0) stays as the
// cross-wave drain pin before each barrier. Happens-before chain:
//   region X last-read drains at reader's lgkm(0) in phase p (pre-bar(p+1));
//   X's overwriting STAGE is issued post-bar(p+1) or later. Publish of tile
//   T+1: vmcnt(8) at ph3 end, then ph0 barrier, then reads.
// Wait table: ph3(T) outstanding = 8(T+1) + 8(T+2 if staged); need T+1
// drained -> vmcnt(8) iff T+2<NT else vmcnt(0).
// ---------------------------------------------------------------------------
enum { EPI_BF16 = 0, EPI_F32 = 1, EPI_GELUMUL = 2, EPI_QK = 3, EPI_VSW = 4 };

template <int EPI>
__global__ __launch_bounds__(512, 2) void gemm8p(
    const bf16* __restrict__ A, const bf16* __restrict__ Bw,
    void* __restrict__ Cout, const bf16* __restrict__ aux,
    void* __restrict__ C2, int Ndim, int Kdim, int mshift) {
  __shared__ __align__(16) char L[131072];  // [buf2][op2][row256][col64] bf16

  const int NT = Kdim >> 6;
  const int NB = gridDim.x;
  const int bid = blockIdx.x;
  // XCD-bijective swizzle (NB%8==0 for all shapes), B-panel-major ordering:
  const int sw = (bid & 7) * (NB >> 3) + (bid >> 3);
  const int m0 = (sw & ((1 << mshift) - 1)) << 8;
  const int n0 = (sw >> mshift) << 8;

  const int tid = threadIdx.x;
  const int wid = tid >> 6, l = tid & 63;
  const int wm = wid >> 2, wn = wid & 3;
  const int lr = l & 15, lg = l >> 4;

  // --- staging geometry (linear LDS dest, inverse-swizzled global src) ---
  const int rlane = wid * 16 + (l >> 3);        // row within 128-row half
  const int lc8 = (((l & 7) ^ (l >> 3)) << 3);  // swizzled source col (elems)
  const bf16* srcA = A + (size_t)(m0 + rlane) * Kdim + lc8;
  const bf16* srcB = Bw + (size_t)(n0 + rlane) * Kdim + lc8;
  const size_t K128 = (size_t)Kdim << 7;  // 128 rows of elems
  const size_t K8 = (size_t)Kdim << 3;    // 8 rows

  auto STAGE = [&](int op, int rh, int tl) {
    if (tl >= NT) return;
    const bf16* s = (op ? srcB : srcA) + (size_t)rh * K128 + ((size_t)tl << 6);
    char* d = L + ((tl & 1) << 16) + (op << 15) + (rh << 14) + (wid << 11);
    gl_lds16(s, d);
    gl_lds16(s + K8, d + 1024);
  };

  // --- fragment read geometry (swizzled) ---
  const int arow = wm * 128 + lr;
  const int brow = wn * 64 + lr;
  const int swz = lr & 7;
  const int csw0 = ((0 * 4 + lg) ^ swz) << 4;
  const int csw1 = ((1 * 4 + lg) ^ swz) << 4;
  auto LDA = [&](int mi, int kk, int c) {
    return *(const bf16x8_t*)(L + (c << 16) + arow * 128 + mi * 2048 +
                              (kk ? csw1 : csw0));
  };
  auto LDB = [&](int ni, int kk, int c) {
    return *(const bf16x8_t*)(L + (c << 16) + 32768 + brow * 128 + ni * 2048 +
                              (kk ? csw1 : csw0));
  };

  f32x4_t acc[8][4];
  #pragma unroll
  for (int i = 0; i < 8; i++)
    #pragma unroll
    for (int j = 0; j < 4; j++) acc[i][j] = (f32x4_t){0.f, 0.f, 0.f, 0.f};

  bf16x8_t fa[8][2], fb[4][2];

  // prologue: all of tile 0 and tile 1 (16 loads). vmcnt(8) -> tile 0 done.
  // The publish barrier is TILE's ph0 entry barrier.
  STAGE(1, 0, 0); STAGE(1, 1, 0); STAGE(0, 0, 0); STAGE(0, 1, 0);
  STAGE(1, 0, 1); STAGE(1, 1, 1); STAGE(0, 0, 1); STAGE(0, 1, 1);
  asm volatile("s_waitcnt vmcnt(8)" ::: "memory");

#define MFMA_Q(MB, NBQ)                                                        \
  _Pragma("unroll") for (int mi = 0; mi < 4; ++mi)                             \
  _Pragma("unroll") for (int ni = 0; ni < 2; ++ni) {                           \
    acc[MB + mi][NBQ + ni] =                                                   \
        mfma16(fa[MB + mi][0], fb[NBQ + ni][0], acc[MB + mi][NBQ + ni]);       \
    acc[MB + mi][NBQ + ni] =                                                   \
        mfma16(fa[MB + mi][1], fb[NBQ + ni][1], acc[MB + mi][NBQ + ni]);       \
  }

#define TILE(T, C)                                                             \
  {                                                                            \
    /* ph0: publish barrier (tile T data); reads fa0-3,fb0-1; MFMA Q(0,0) */   \
    __builtin_amdgcn_s_barrier();                                              \
    _Pragma("unroll") for (int mi = 0; mi < 4; ++mi) {                         \
      fa[mi][0] = LDA(mi, 0, (C)); fa[mi][1] = LDA(mi, 1, (C));                \
    }                                                                          \
    _Pragma("unroll") for (int ni = 0; ni < 2; ++ni) {                         \
      fb[ni][0] = LDB(ni, 0, (C)); fb[ni][1] = LDB(ni, 1, (C));                \
    }                                                                          \
    asm volatile("s_waitcnt lgkmcnt(0)" ::: "memory");                         \
    __builtin_amdgcn_s_setprio(1);                                             \
    MFMA_Q(0, 0);                                                              \
    __builtin_amdgcn_s_setprio(0);                                             \
    /* ph1: reads fb2-3 pre-barrier; MFMA Q(0,2) */                            \
    _Pragma("unroll") for (int ni = 2; ni < 4; ++ni) {                         \
      fb[ni][0] = LDB(ni, 0, (C)); fb[ni][1] = LDB(ni, 1, (C));                \
    }                                                                          \
    __builtin_amdgcn_s_barrier();                                              \
    asm volatile("s_waitcnt lgkmcnt(0)" ::: "memory");                         \
    __builtin_amdgcn_s_setprio(1);                                             \
    MFMA_Q(0, 2);                                                              \
    __builtin_amdgcn_s_setprio(0);                                             \
    /* ph2: reads fa4-7 pre-barrier; stage B(T+2) post-drain; MFMA Q(4,0) */   \
    _Pragma("unroll") for (int mi = 4; mi < 8; ++mi) {                         \
      fa[mi][0] = LDA(mi, 0, (C)); fa[mi][1] = LDA(mi, 1, (C));                \
    }                                                                          \
    __builtin_amdgcn_s_barrier();                                              \
    asm volatile("s_waitcnt lgkmcnt(0)" ::: "memory");                         \
    STAGE(1, 0, (T) + 2);                                                      \
    STAGE(1, 1, (T) + 2);                                                      \
    __builtin_amdgcn_s_setprio(1);                                             \
    MFMA_Q(4, 0);                                                              \
    __builtin_amdgcn_s_setprio(0);                                             \
    /* ph3: barrier; stage A(T+2); MFMA Q(4,2) from regs; tail-aware vmcnt */  \
    __builtin_amdgcn_s_barrier();                                              \
    STAGE(0, 0, (T) + 2);                                                      \
    STAGE(0, 1, (T) + 2);                                                      \
    __builtin_amdgcn_s_setprio(1);                                             \
    MFMA_Q(4, 2);                                                              \
    __builtin_amdgcn_s_setprio(0);                                             \
    if ((T) + 2 < NT) {                                                        \
      asm volatile("s_waitcnt vmcnt(8)" ::: "memory");                         \
    } else {                                                                   \
      asm volatile("s_waitcnt vmcnt(0)" ::: "memory");                         \
    }                                                                          \
  }

  for (int t = 0; t < NT; t += 2) {
    TILE(t, 0);
    TILE(t + 1, 1);
  }
#undef TILE
#undef MFMA_Q

  // Epilogue. C/D layout: col = lane&15, row = (lane>>4)*4 + reg.
  const int row0 = m0 + wm * 128 + lg * 4;
  const int col0 = n0 + wn * 64 + lr;
  #pragma unroll
  for (int mi = 0; mi < 8; mi++) {
    #pragma unroll
    for (int ni = 0; ni < 4; ni++) {
      #pragma unroll
      for (int r = 0; r < 4; r++) {
        const int row = row0 + mi * 16 + r;
        const int col = col0 + ni * 16;
        const float v = acc[mi][ni][r];
        if constexpr (EPI == EPI_BF16) {
          ((bf16*)Cout)[(size_t)row * Ndim + col] = __float2bfloat16(v);
        } else if constexpr (EPI == EPI_F32) {
          ((float*)Cout)[(size_t)row * Ndim + col] = v;
        } else if constexpr (EPI == EPI_QK) {
          // cols [0,4096) -> q (row-major); [4096,6144) -> k (row-major).
          if (col < 4096) {
            ((bf16*)Cout)[(size_t)row * 4096 + col] = __float2bfloat16(v);
          } else {
            ((bf16*)C2)[(size_t)row * 2048 + (col - 4096)] =
                __float2bfloat16(v);
          }
        } else if constexpr (EPI == EPI_VSW) {
          // swapped V GEMM: row = kv-dim (kvh*256+d), col = token (b*2048+s).
          const int bb = col >> 11, s = col & 2047;
          ((bf16*)Cout)[(((size_t)((bb * 8 + (row >> 8)) * 256 + (row & 255)))
                         << 11) + s] = __float2bfloat16(v);
        } else {  // EPI_GELUMUL
          const float g = __bfloat162float(aux[(size_t)row * Ndim + col]);
          const float u = 0.7978845608028654f * (g + 0.044715f * g * g * g);
          const float gl = 0.5f * g * (1.f + tanhf(u));
          ((bf16*)Cout)[(size_t)row * Ndim + col] = __float2bfloat16(gl * v);
        }
      }
    }
  }
  (void)aux; (void)C2;
}

// ---------------------------------------------------------------------------
// RMSNorm of input hidden -> bf16
// ---------------------------------------------------------------------------
__global__ __launch_bounds__(256) void rmsnorm_in(
    const float* __restrict__ x, const float* __restrict__ w,
    bf16* __restrict__ out) {
  const int row = blockIdx.x, t = threadIdx.x;
  const float4* xr = (const float4*)(x + (size_t)row * HID);
  float4 v[4];
  float ss = 0.f;
  #pragma unroll
  for (int j = 0; j < 4; j++) {
    const int idx = t + 256 * j;
    if (idx < HID / 4) {
      v[j] = xr[idx];
      ss += v[j].x * v[j].x + v[j].y * v[j].y + v[j].z * v[j].z + v[j].w * v[j].w;
    }
  }
  ss = block_reduce_sum(ss);
  const float sc = rsqrtf(ss * (1.f / HID) + EPSF);
  const float4* w4 = (const float4*)w;
  bf16* orow = out + (size_t)row * HID;
  #pragma unroll
  for (int j = 0; j < 4; j++) {
    const int idx = t + 256 * j;
    if (idx < HID / 4) {
      const float4 wv = w4[idx];
      ushort4 o;
      o.x = f2bu(v[j].x * sc * (1.f + wv.x));
      o.y = f2bu(v[j].y * sc * (1.f + wv.y));
      o.z = f2bu(v[j].z * sc * (1.f + wv.z));
      o.w = f2bu(v[j].w * sc * (1.f + wv.w));
      *(ushort4*)(orow + idx * 4) = o;
    }
  }
}

// ---------------------------------------------------------------------------
// RoPE in-place on q (16 heads) and k (8 heads), bf16.
// ---------------------------------------------------------------------------
__global__ __launch_bounds__(128) void rope_kernel(
    bf16* __restrict__ q, bf16* __restrict__ k,
    const float* __restrict__ cosb, const float* __restrict__ sinb) {
  const int tok = blockIdx.x;
  const int hs = blockIdx.y;
  const int d = threadIdx.x;  // 0..127
  const int s = tok & (SEQ - 1);
  bf16* ptr = (hs < NHEADS)
                  ? q + (size_t)tok * QOUT + hs * HDIM
                  : k + (size_t)tok * KOUT + (hs - NHEADS) * HDIM;
  const float c = cosb[s * HDIM + d];
  const float sn = sinb[s * HDIM + d];
  const float x0 = __bfloat162float(ptr[d]);
  const float x1 = __bfloat162float(ptr[d + 128]);
  ptr[d] = __float2bfloat16(x0 * c - x1 * sn);
  ptr[d + 128] = __float2bfloat16(x1 * c + x0 * sn);
}

// ---------------------------------------------------------------------------
// Flash attention, sliding window 1024, softcap 50, fixed-base softmax.
// ---------------------------------------------------------------------------
__global__ __launch_bounds__(256) void attn_kernel(
    const bf16* __restrict__ q, const bf16* __restrict__ k,
    const bf16* __restrict__ vt, bf16* __restrict__ out) {
  __shared__ __align__(16) bf16 plds[4][16 * 32];

  const int qt = blockIdx.x, h = blockIdx.y, b = blockIdx.z;
  const int w = threadIdx.x >> 6, l = threadIdx.x & 63;
  const int kvh = h >> 1;
  const int qbase = qt * 64 + w * 16;
  const int lr = l & 15, lg = l >> 4, lk = lg * 8;

  bf16x8_t qf[8];
  const bf16* qrow = q + (size_t)(b * SEQ + qbase + lr) * QOUT + h * HDIM;
  #pragma unroll
  for (int c = 0; c < 8; c++) qf[c] = *(const bf16x8_t*)(qrow + c * 32 + lk);

  f32x4_t acc[16];
  #pragma unroll
  for (int i = 0; i < 16; i++) acc[i] = (f32x4_t){0.f, 0.f, 0.f, 0.f};
  float L[4] = {0.f, 0.f, 0.f, 0.f};

  const bf16* kp = k + (size_t)(b * SEQ) * KOUT + kvh * HDIM;
  const bf16* vp = vt + (size_t)(b * NKVH + kvh) * HDIM * SEQ;
  bf16* pl = &plds[w][0];

  int kstart = qbase - 1023;
  if (kstart < 0) kstart = 0;
  kstart &= ~31;
  const int kend = qbase + 15;

  for (int kb = kstart; kb <= kend; kb += 32) {
    f32x4_t s0 = (f32x4_t){0.f, 0.f, 0.f, 0.f};
    f32x4_t s1 = (f32x4_t){0.f, 0.f, 0.f, 0.f};
    #pragma unroll
    for (int c = 0; c < 8; c++) {
      bf16x8_t k0 = *(const bf16x8_t*)(kp + (size_t)(kb + lr) * KOUT + c * 32 + lk);
      bf16x8_t k1 = *(const bf16x8_t*)(kp + (size_t)(kb + 16 + lr) * KOUT + c * 32 + lk);
      s0 = mfma16(qf[c], k0, s0);
      s1 = mfma16(qf[c], k1, s1);
    }
    float p[8];
    #pragma unroll
    for (int sub = 0; sub < 2; sub++) {
      const int j = kb + sub * 16 + lr;
      #pragma unroll
      for (int r = 0; r < 4; r++) {
        const int i = qbase + lg * 4 + r;
        float sc = (sub ? s1[r] : s0[r]) * 0.0625f;
        sc = 50.f * tanhf(sc * 0.02f);
        const bool ok = (j <= i) && (j > i - 1024);
        p[sub * 4 + r] = ok ? __expf(sc) : 0.f;
      }
    }
    #pragma unroll
    for (int r = 0; r < 4; r++) {
      float ps = p[r] + p[4 + r];
      ps += __shfl_xor(ps, 1, 64);
      ps += __shfl_xor(ps, 2, 64);
      ps += __shfl_xor(ps, 4, 64);
      ps += __shfl_xor(ps, 8, 64);
      L[r] += ps;
    }
    #pragma unroll
    for (int sub = 0; sub < 2; sub++)
      #pragma unroll
      for (int r = 0; r < 4; r++)
        pl[(lg * 4 + r) * 32 + sub * 16 + lr] = __float2bfloat16(p[sub * 4 + r]);
    asm volatile("s_waitcnt lgkmcnt(0)" ::: "memory");
    const bf16x8_t pa = *(const bf16x8_t*)(pl + lr * 32 + lk);
    #pragma unroll
    for (int dt = 0; dt < 16; dt++) {
      bf16x8_t bv = *(const bf16x8_t*)(vp + (size_t)(dt * 16 + lr) * SEQ + kb + lk);
      acc[dt] = mfma16(pa, bv, acc[dt]);
    }
  }

  float rL[4];
  #pragma unroll
  for (int r = 0; r < 4; r++) rL[r] = 1.f / L[r];
  #pragma unroll
  for (int dt = 0; dt < 16; dt++) {
    #pragma unroll
    for (int r = 0; r < 4; r++) {
      const int tok = b * SEQ + qbase + lg * 4 + r;
      out[(size_t)tok * QOUT + h * HDIM + dt * 16 + lr] =
          __float2bfloat16(acc[dt][r] * rL[r]);
    }
  }
}

// ---------------------------------------------------------------------------
// fuse1: h1 = hidden + rmsnorm(attn_proj, w_post); y = bf16(rmsnorm(h1, w_pre))
// ---------------------------------------------------------------------------
__global__ __launch_bounds__(256) void fuse_attn(
    const float* __restrict__ hidden, const float* __restrict__ ap,
    const float* __restrict__ w_post, const float* __restrict__ w_pre,
    float* __restrict__ h1, bf16* __restrict__ y) {
  const int row = blockIdx.x, t = threadIdx.x;
  const float4* ar = (const float4*)(ap + (size_t)row * HID);
  const float4* hr = (const float4*)(hidden + (size_t)row * HID);
  float4 a[4];
  float ss = 0.f;
  #pragma unroll
  for (int j = 0; j < 4; j++) {
    const int idx = t + 256 * j;
    if (idx < HID / 4) {
      a[j] = ar[idx];
      ss += a[j].x * a[j].x + a[j].y * a[j].y + a[j].z * a[j].z + a[j].w * a[j].w;
    }
  }
  ss = block_reduce_sum(ss);
  const float sc = rsqrtf(ss * (1.f / HID) + EPSF);
  const float4* wpo = (const float4*)w_post;
  float4* h1r = (float4*)(h1 + (size_t)row * HID);
  float4 hv[4];
  float ss2 = 0.f;
  #pragma unroll
  for (int j = 0; j < 4; j++) {
    const int idx = t + 256 * j;
    if (idx < HID / 4) {
      const float4 wv = wpo[idx];
      const float4 x = hr[idx];
      hv[j].x = x.x + a[j].x * sc * (1.f + wv.x);
      hv[j].y = x.y + a[j].y * sc * (1.f + wv.y);
      hv[j].z = x.z + a[j].z * sc * (1.f + wv.z);
      hv[j].w = x.w + a[j].w * sc * (1.f + wv.w);
      ss2 += hv[j].x * hv[j].x + hv[j].y * hv[j].y + hv[j].z * hv[j].z + hv[j].w * hv[j].w;
      h1r[idx] = hv[j];
    }
  }
  ss2 = block_reduce_sum(ss2);
  const float sc2 = rsqrtf(ss2 * (1.f / HID) + EPSF);
  const float4* wpr = (const float4*)w_pre;
  bf16* yr = y + (size_t)row * HID;
  #pragma unroll
  for (int j = 0; j < 4; j++) {
    const int idx = t + 256 * j;
    if (idx < HID / 4) {
      const float4 wv = wpr[idx];
      ushort4 o;
      o.x = f2bu(hv[j].x * sc2 * (1.f + wv.x));
      o.y = f2bu(hv[j].y * sc2 * (1.f + wv.y));
      o.z = f2bu(hv[j].z * sc2 * (1.f + wv.z));
      o.w = f2bu(hv[j].w * sc2 * (1.f + wv.w));
      *(ushort4*)(yr + idx * 4) = o;
    }
  }
}

// ---------------------------------------------------------------------------
// fuse2: out = h1 + rmsnorm(mlp, w_post_ff)
// ---------------------------------------------------------------------------
__global__ __launch_bounds__(256) void fuse_out(
    const float* __restrict__ h1, const float* __restrict__ mlp,
    const float* __restrict__ w, float* __restrict__ out) {
  const int row = blockIdx.x, t = threadIdx.x;
  const float4* mr = (const float4*)(mlp + (size_t)row * HID);
  float4 m[4];
  float ss = 0.f;
  #pragma unroll
  for (int j = 0; j < 4; j++) {
    const int idx = t + 256 * j;
    if (idx < HID / 4) {
      m[j] = mr[idx];
      ss += m[j].x * m[j].x + m[j].y * m[j].y + m[j].z * m[j].z + m[j].w * m[j].w;
    }
  }
  ss = block_reduce_sum(ss);
  const float sc = rsqrtf(ss * (1.f / HID) + EPSF);
  const float4* hr = (const float4*)(h1 + (size_t)row * HID);
  const float4* w4 = (const float4*)w;
  float4* orow = (float4*)(out + (size_t)row * HID);
  #pragma unroll
  for (int j = 0; j < 4; j++) {
    const int idx = t + 256 * j;
    if (idx < HID / 4) {
      const float4 wv = w4[idx];
      const float4 x = hr[idx];
      float4 o;
      o.x = x.x + m[j].x * sc * (1.f + wv.x);
      o.y = x.y + m[j].y * sc * (1.f + wv.y);
      o.z = x.z + m[j].z * sc * (1.f + wv.z);
      o.w = x.w + m[j].w * sc * (1.f + wv.w);
      orow[idx] = o;
    }
  }
}

// ---------------------------------------------------------------------------
extern "C" void kernel_launch(void* const* d_in, const int* in_sizes, int n_in,
                              void* d_out, int out_size, void* d_ws,
                              size_t ws_size, hipStream_t stream) {
  const float* hidden = (const float*)d_in[0];
  const float* cosb = (const float*)d_in[1];
  const float* sinb = (const float*)d_in[2];
  const float* Wq = (const float*)d_in[3];
  const float* Wk = (const float*)d_in[4];
  const float* Wv = (const float*)d_in[5];
  const float* Wo = (const float*)d_in[6];
  const float* Wgate = (const float*)d_in[7];
  const float* Wup = (const float*)d_in[8];
  const float* Wdown = (const float*)d_in[9];
  const float* w_in = (const float*)d_in[10];
  const float* w_post_attn = (const float*)d_in[11];
  const float* w_pre_ff = (const float*)d_in[12];
  const float* w_post_ff = (const float*)d_in[13];
  float* out = (float*)d_out;

  (void)in_sizes; (void)n_in; (void)out_size; (void)ws_size;

  const size_t WB = 102760448;  // 14336*3584*2 — bf16 weight scratch
  char* ws = (char*)d_ws;
  bf16* wbuf = (bf16*)ws;
  char* ab = ws + WB;

  // Region 0 (63 MB): xn + q -> attn_proj -> mlp
  bf16* xn = (bf16*)(ab);
  bf16* q = (bf16*)(ab + 29360128);
  float* attn_proj = (float*)(ab);
  float* mlp = (float*)(ab);
  // Region 1 (67 MB): k + vt + attn_out -> h1
  bf16* kbuf = (bf16*)(ab + 62914560);
  bf16* vt = (bf16*)(ab + 62914560 + 16777216);
  bf16* attn_out = (bf16*)(ab + 62914560 + 33554432);
  float* h1 = (float*)(ab + 62914560);
  // Region 2: y
  bf16* y = (bf16*)(ab + 130023424);
  // Region 3: gate (gelu*up written in-place)
  bf16* gate = (bf16*)(ab + 159383552);

  rmsnorm_in<<<MTOK, 256, 0, stream>>>(hidden, w_in, xn);

  // wbuf rows [0,4096)=Wq, [4096,6144)=Wk, [6144,8192)=Wv
  cvt_w<<<4096, 256, 0, stream>>>(Wq, wbuf, QOUT * HID);
  cvt_w<<<2048, 256, 0, stream>>>(Wk, wbuf + (size_t)QOUT * HID, KOUT * HID);
  cvt_w<<<2048, 256, 0, stream>>>(Wv, wbuf + (size_t)(QOUT + KOUT) * HID,
                                  KOUT * HID);
  // QK: N=6144 (q rows + k rows), coalesced row-major outputs.
  gemm8p<EPI_QK><<<(6144 / 256) * 16, 512, 0, stream>>>(
      xn, wbuf, q, nullptr, kbuf, 6144, HID, 4);
  // V swapped: vt[kv][tok] = Wv[kv][h] * xn[tok][h]^T; M=2048 (mshift=3).
  gemm8p<EPI_VSW><<<(4096 / 256) * 8, 512, 0, stream>>>(
      wbuf + (size_t)(QOUT + KOUT) * HID, xn, vt, nullptr, nullptr,
      4096, HID, 3);
  rope_kernel<<<dim3(MTOK, NHEADS + NKVH), 128, 0, stream>>>(q, kbuf, cosb, sinb);
  attn_kernel<<<dim3(SEQ / 64, NHEADS, NBATCH), 256, 0, stream>>>(
      q, kbuf, vt, attn_out);
  cvt_w<<<4096, 256, 0, stream>>>(Wo, wbuf, HID * QOUT);
  gemm8p<EPI_F32><<<(HID / 256) * 16, 512, 0, stream>>>(
      attn_out, wbuf, attn_proj, nullptr, nullptr, HID, QOUT, 4);
  fuse_attn<<<MTOK, 256, 0, stream>>>(hidden, attn_proj, w_post_attn,
                                      w_pre_ff, h1, y);
  cvt_w<<<4096, 256, 0, stream>>>(Wgate, wbuf, INTERD * HID);
  gemm8p<EPI_BF16><<<(INTERD / 256) * 16, 512, 0, stream>>>(
      y, wbuf, gate, nullptr, nullptr, INTERD, HID, 4);
  cvt_w<<<4096, 256, 0, stream>>>(Wup, wbuf, INTERD * HID);
  gemm8p<EPI_GELUMUL><<<(INTERD / 256) * 16, 512, 0, stream>>>(
      y, wbuf, gate, gate, nullptr, INTERD, HID, 4);
  cvt_w<<<4096, 256, 0, stream>>>(Wdown, wbuf, HID * INTERD);
  gemm8p<EPI_F32><<<(HID / 256) * 16, 512, 0, stream>>>(
      gate, wbuf, mlp, nullptr, nullptr, HID, INTERD, 4);

  fuse_out<<<MTOK, 256, 0, stream>>>(h1, mlp, w_post_ff, out);
}